// Round 11
// baseline (46275.183 us; speedup 1.0000x reference)
//
#include <hip/hip_runtime.h>

// PyramidSampler: B=4 clouds of P=8192 pts, D=512 feats, scales (1.0, 0.5, 0.25).
// Scale 0.25's FPS indices are an exact prefix of scale 0.5's -> one 4096-step
// FPS per batch.
//
// R9 (resubmitted R10 after acquisition timeout): SINGLE-WAVE FPS (64 threads
// per block, 1 wave). Rationale: R4-R7 cut VALU issue ~2x and LDS traffic ~8x
// with ZERO time change -> per-step cost is a fixed floor invariant to issued
// work. Candidate explanations: core clock (4-CU workload may never boost) or
// barrier/wave-skew. This kernel removes EVERY barrier and cross-wave
// structure: one wave per batch, lane-lockstep, argmax purely in-register via
// DPP, winner via readlane. Per-step critical path is ~850 cycles by
// construction -> measured time reveals the clock.
//   - 128 pts/lane as 8 groups of 16, Morton-sorted ownership.
//   - dist[128] in VGPRs; coords read from LDS A (orig order) only for ACTIVE
//     groups (masked); keys from LDS B for lo1.
//   - 2-level register-bbox pruning: 2 clusters of 4 groups, then groups.
//     Skip is provable-exact (lb2*0.999995 >= cached max, proven R2-R7).
//   - group winner coords fetched by index (A[3*(8192-lob)]) and cached, so
//     the wave winner's coords ride the DPP6 reduce -> no centroid fetch.
// Exact math: no fma, (dx^2+dy^2)+dz^2 left fold, min-update, global argmax
// ties -> smallest orig idx (max lo1 = 8192-o). absmax 0.0 in R1-R7.

constexpr int kB   = 4;
constexpr int kP   = 8192;
constexpr int kD   = 512;
constexpr int kN1  = 4096;              // int(P*0.5)
constexpr int kN2  = 2048;              // int(P*0.25)
constexpr int kS   = kP + kN1 + kN2;    // 14336 rows per batch
constexpr int kTF  = 64;                // ONE wave per block
constexpr int kPts = kP / kTF;          // 128 points per lane
constexpr int kG   = 8;                 // groups per lane
constexpr int kGp  = kPts / kG;         // 16 points per group
constexpr int kC   = 2;                 // clusters per lane (4 groups each)

typedef unsigned long long u64;
typedef unsigned u32;

template <int CTRL>
__device__ __forceinline__ u32 dpp1(u32 v) {
  return (u32)__builtin_amdgcn_update_dpp((int)v, (int)v, CTRL, 0xF, 0xF, false);
}

// combined argmax key: (dist f32, lo1 u32 tie-break, coords as bits)
__device__ __forceinline__ void keymax(float& d, u32& l, u32& x, u32& y, u32& z,
                                       float od, u32 ol, u32 ox, u32 oy, u32 oz) {
  bool t = (od > d) || (od == d && ol > l);
  d = t ? od : d; l = t ? ol : l;
  x = t ? ox : x; y = t ? oy : y; z = t ? oz : z;
}

#define DPP_STAGE(CTRL)                                                     \
  {                                                                         \
    u32 pd = dpp1<CTRL>(__float_as_uint(kd));                               \
    u32 pl = dpp1<CTRL>(kl);                                                \
    u32 qx = dpp1<CTRL>(kx);                                                \
    u32 qy = dpp1<CTRL>(ky);                                                \
    u32 qz = dpp1<CTRL>(kz);                                                \
    keymax(kd, kl, kx, ky, kz, __uint_as_float(pd), pl, qx, qy, qz);        \
  }

// full-wave reduce; result valid in lanes 48..63 (read lane 63). Proven R4-R7.
#define DPP_REDUCE6()                                                       \
  DPP_STAGE(0xB1);  /* quad_perm xor1 */                                    \
  DPP_STAGE(0x4E);  /* quad_perm xor2 */                                    \
  DPP_STAGE(0x141); /* row_half_mirror */                                   \
  DPP_STAGE(0x140); /* row_mirror */                                        \
  DPP_STAGE(0x142); /* row_bcast15 */                                       \
  DPP_STAGE(0x143); /* row_bcast31 */

__global__ __launch_bounds__(kTF, 1)
void fps_kernel(const float* __restrict__ pos, int* __restrict__ idx_out) {
  const int b   = blockIdx.x;
  const int tid = threadIdx.x;            // == lane (one wave)
  const float* pb = pos + (size_t)b * kP * 3;
  int* idx = idx_out + b * kN1;

  __shared__ __attribute__((aligned(16))) float A[kP * 3];   // 96 KB orig-order coords
  __shared__ __attribute__((aligned(16))) u32 Bk[kP];        // 32 KB sorted keys
  __shared__ __attribute__((aligned(16))) u32 IDX[kN1];      // 16 KB idx buffer

  // ---- 1) stage pos into LDS (coalesced float4) ----
  {
    const float4* src = reinterpret_cast<const float4*>(pb);
    float4* dst = reinterpret_cast<float4*>(A);
    for (int i = 0; i < (kP * 3 / 4) / kTF; ++i)       // 96 iters
      dst[tid + i * kTF] = src[tid + i * kTF];
  }
  __syncthreads();

  // ---- 2) cloud bbox (64-lane shfl reduce) ----
  float mn0 = 1e30f, mn1 = 1e30f, mn2 = 1e30f;
  float mx0 = -1e30f, mx1 = -1e30f, mx2 = -1e30f;
  for (int i = tid; i < kP; i += kTF) {
    float x = A[3 * i], y = A[3 * i + 1], z = A[3 * i + 2];
    mn0 = fminf(mn0, x); mx0 = fmaxf(mx0, x);
    mn1 = fminf(mn1, y); mx1 = fmaxf(mx1, y);
    mn2 = fminf(mn2, z); mx2 = fmaxf(mx2, z);
  }
#pragma unroll
  for (int m = 32; m >= 1; m >>= 1) {
    mn0 = fminf(mn0, __shfl_xor(mn0, m, 64)); mx0 = fmaxf(mx0, __shfl_xor(mx0, m, 64));
    mn1 = fminf(mn1, __shfl_xor(mn1, m, 64)); mx1 = fmaxf(mx1, __shfl_xor(mx1, m, 64));
    mn2 = fminf(mn2, __shfl_xor(mn2, m, 64)); mx2 = fmaxf(mx2, __shfl_xor(mx2, m, 64));
  }

  // ---- 3) Morton keys: 18-bit code << 13 | orig idx ----
  {
    const float i0 = 63.0f / fmaxf(mx0 - mn0, 1e-20f);
    const float i1 = 63.0f / fmaxf(mx1 - mn1, 1e-20f);
    const float i2 = 63.0f / fmaxf(mx2 - mn2, 1e-20f);
    for (int i = tid; i < kP; i += kTF) {
      int qx = (int)((A[3 * i]     - mn0) * i0);
      int qy = (int)((A[3 * i + 1] - mn1) * i1);
      int qz = (int)((A[3 * i + 2] - mn2) * i2);
      qx = min(max(qx, 0), 63); qy = min(max(qy, 0), 63); qz = min(max(qz, 0), 63);
      u32 code = 0;
#pragma unroll
      for (int t = 0; t < 6; ++t)
        code |= (((u32)(qx >> t) & 1u) << (3 * t)) |
                (((u32)(qy >> t) & 1u) << (3 * t + 1)) |
                (((u32)(qz >> t) & 1u) << (3 * t + 2));
      Bk[i] = (code << 13) | (u32)i;
    }
  }
  __syncthreads();

  // ---- 4) bitonic sort of 8192 u32 keys (setup; 1-wave barriers cheap) ----
  for (int kk = 2; kk <= kP; kk <<= 1) {
    for (int j = kk >> 1; j > 0; j >>= 1) {
      const int mask = j - 1;
      for (int it = 0; it < (kP / 2) / kTF; ++it) {    // 64 iters
        int i = tid + it * kTF;
        int a = ((i & ~mask) << 1) | (i & mask);
        int c = a | j;
        u32 x = Bk[a], y = Bk[c];
        bool up = ((a & kk) == 0);
        if ((x > y) == up) { Bk[a] = y; Bk[c] = x; }
      }
      __syncthreads();
    }
  }

  // ---- 5) ownership: dist regs + group/cluster bboxes + cached group keys ----
  float dist_[kPts];
  float gbl[kG][3], gbh[kG][3];          // group bbox lo/hi
  float gd[kG]; u32 gl[kG], gxc[kG], gyc[kG], gzc[kG];
#pragma unroll
  for (int g = 0; g < kG; ++g) {
    gbl[g][0] = 1e30f; gbl[g][1] = 1e30f; gbl[g][2] = 1e30f;
    gbh[g][0] = -1e30f; gbh[g][1] = -1e30f; gbh[g][2] = -1e30f;
    gd[g] = 1e10f; gl[g] = 0; gxc[g] = 0; gyc[g] = 0; gzc[g] = 0;
  }
#pragma unroll
  for (int m = 0; m < kPts; ++m) {
    const int g = m / kGp;
    u32 o = Bk[tid * kPts + m] & 8191u;
    float x = A[3 * o], y = A[3 * o + 1], z = A[3 * o + 2];
    gbl[g][0] = fminf(gbl[g][0], x); gbh[g][0] = fmaxf(gbh[g][0], x);
    gbl[g][1] = fminf(gbl[g][1], y); gbh[g][1] = fmaxf(gbh[g][1], y);
    gbl[g][2] = fminf(gbl[g][2], z); gbh[g][2] = fmaxf(gbh[g][2], z);
    dist_[m] = 1e10f;
    u32 lo1 = 8192u - o;                 // unique, >0; max lo1 = smallest idx
    bool t = lo1 > gl[g];                // all dists equal at init
    gl[g]  = t ? lo1 : gl[g];
    gxc[g] = t ? __float_as_uint(x) : gxc[g];
    gyc[g] = t ? __float_as_uint(y) : gyc[g];
    gzc[g] = t ? __float_as_uint(z) : gzc[g];
  }
  float cbl[kC][3], cbh[kC][3];          // cluster bbox (4 groups each)
#pragma unroll
  for (int c = 0; c < kC; ++c) {
#pragma unroll
    for (int d3 = 0; d3 < 3; ++d3) {
      float lo = gbl[4 * c][d3], hi = gbh[4 * c][d3];
#pragma unroll
      for (int g = 1; g < 4; ++g) {
        lo = fminf(lo, gbl[4 * c + g][d3]);
        hi = fmaxf(hi, gbh[4 * c + g][d3]);
      }
      cbl[c][d3] = lo; cbh[c][d3] = hi;
    }
  }
  // lane-best cache (recomputed only when a lane group updates)
  float lbd = gd[0]; u32 lbl = gl[0], lbx = gxc[0], lby = gyc[0], lbz = gzc[0];
#pragma unroll
  for (int g = 1; g < kG; ++g)
    keymax(lbd, lbl, lbx, lby, lbz, gd[g], gl[g], gxc[g], gyc[g], gzc[g]);

  // initial centroid = orig point 0 (deterministic start)
  float cx = A[0], cy = A[1], cz = A[2];
  int far = 0;

  // ---- 6) main loop: NO barrier, NO cross-wave, no vmem ----
  for (int s = 0; ; ++s) {
    if (tid == 0) IDX[s] = (u32)far;
    if (s == kN1 - 1) break;

    bool ag[kG];
#pragma unroll
    for (int c = 0; c < kC; ++c) {
      float gx = fmaxf(fmaxf(cbl[c][0] - cx, cx - cbh[c][0]), 0.0f);
      float gy = fmaxf(fmaxf(cbl[c][1] - cy, cy - cbh[c][1]), 0.0f);
      float gz = fmaxf(fmaxf(cbl[c][2] - cz, cz - cbh[c][2]), 0.0f);
      float lb2c = gx * gx + gy * gy; lb2c = lb2c + gz * gz;
      float cmax = fmaxf(fmaxf(gd[4 * c], gd[4 * c + 1]),
                         fmaxf(gd[4 * c + 2], gd[4 * c + 3]));
      bool ca = !(lb2c * 0.999995f >= cmax);
#pragma unroll
      for (int gg = 0; gg < 4; ++gg) ag[4 * c + gg] = false;
      if (ca) {                           // divergent; execz-skips when no lane
#pragma unroll
        for (int gg = 0; gg < 4; ++gg) {
          const int g = 4 * c + gg;
          float hx = fmaxf(fmaxf(gbl[g][0] - cx, cx - gbh[g][0]), 0.0f);
          float hy = fmaxf(fmaxf(gbl[g][1] - cy, cy - gbh[g][1]), 0.0f);
          float hz = fmaxf(fmaxf(gbl[g][2] - cz, cz - gbh[g][2]), 0.0f);
          float lb2 = hx * hx + hy * hy; lb2 = lb2 + hz * hz;
          ag[g] = !(lb2 * 0.999995f >= gd[g]);
        }
      }
    }

    bool la = false;
#pragma unroll
    for (int g = 0; g < kG; ++g) {
      if (ag[g]) {                        // masked body, rare
        la = true;
        const u32* bp = &Bk[tid * kPts + g * kGp];
        u32 kk_[kGp];
#pragma unroll
        for (int q = 0; q < kGp / 4; ++q) {
          uint4 qq = *reinterpret_cast<const uint4*>(bp + 4 * q);
          kk_[4 * q] = qq.x; kk_[4 * q + 1] = qq.y;
          kk_[4 * q + 2] = qq.z; kk_[4 * q + 3] = qq.w;
        }
        {
#pragma clang fp contract(off)
#pragma unroll
          for (int j = 0; j < kGp; ++j) {
            u32 o = kk_[j] & 8191u;
            float dx = A[3 * o]     - cx;
            float dy = A[3 * o + 1] - cy;
            float dz = A[3 * o + 2] - cz;
            float d = dx * dx + dy * dy;  // exact mul/add (XLA left fold)
            d = d + dz * dz;
            dist_[g * kGp + j] = fminf(dist_[g * kGp + j], d);
          }
        }
        float vb = dist_[g * kGp];
#pragma unroll
        for (int j = 1; j < kGp; ++j) vb = fmaxf(vb, dist_[g * kGp + j]);
        u32 lob = 0;
#pragma unroll
        for (int j = 0; j < kGp; ++j) {
          u32 lo1 = 8192u - (kk_[j] & 8191u);
          u32 c2 = (dist_[g * kGp + j] == vb) ? lo1 : 0u;
          lob = lob > c2 ? lob : c2;
        }
        const int ow = (int)(8192u - lob);     // group winner orig idx
        gd[g] = vb; gl[g] = lob;
        gxc[g] = __float_as_uint(A[3 * ow]);
        gyc[g] = __float_as_uint(A[3 * ow + 1]);
        gzc[g] = __float_as_uint(A[3 * ow + 2]);
      }
    }

    if (la) {                             // masked lane-best rebuild
      lbd = gd[0]; lbl = gl[0]; lbx = gxc[0]; lby = gyc[0]; lbz = gzc[0];
#pragma unroll
      for (int g = 1; g < kG; ++g)
        keymax(lbd, lbl, lbx, lby, lbz, gd[g], gl[g], gxc[g], gyc[g], gzc[g]);
    }

    // full-wave DPP argmax (exec must be full here: outside all branches)
    float kd = lbd; u32 kl = lbl, kx = lbx, ky = lby, kz = lbz;
    DPP_REDUCE6();
    u32 wl = (u32)__builtin_amdgcn_readlane((int)kl, 63);
    far = (int)(8192u - wl);
    cx = __uint_as_float(__builtin_amdgcn_readlane((int)kx, 63));
    cy = __uint_as_float(__builtin_amdgcn_readlane((int)ky, 63));
    cz = __uint_as_float(__builtin_amdgcn_readlane((int)kz, 63));
  }

  // ---- 7) flush idx buffer to global (coalesced) ----
  __syncthreads();
  {
    const uint4* src = reinterpret_cast<const uint4*>(IDX);
    uint4* dst = reinterpret_cast<uint4*>(idx);
    for (int i = 0; i < (kN1 / 4) / kTF; ++i)          // 16 iters
      dst[tid + i * kTF] = src[tid + i * kTF];
  }
}

// ---------------------------------------------------------------------------
// Gather/assemble kernel (unchanged — proven bit-exact).
// fused_x: [B][14336][512] then fused_p: [B][14336][3].
// ---------------------------------------------------------------------------
constexpr int kXRows     = kB * kS;                    // 57344
constexpr int kXBlocks   = kXRows / 2;                 // 28672
constexpr int kPosElems  = kB * kS * 3;                // 172032
constexpr int kPosBlocks = kPosElems / 256;            // 672

__device__ __forceinline__ int src_row(int b, int r, const int* __restrict__ idx) {
  int s;
  if (r < kP)            s = r;
  else if (r < kP + kN1) s = idx[b * kN1 + (r - kP)];
  else                   s = idx[b * kN1 + (r - kP - kN1)];
  return b * kP + s;
}

__global__ __launch_bounds__(256)
void gather_kernel(const float* __restrict__ x, const float* __restrict__ pos,
                   const int* __restrict__ idx, float* __restrict__ out) {
  const int blk = blockIdx.x;
  if (blk < kXBlocks) {
    const int row  = blk * 2 + (threadIdx.x >> 7);    // 2 rows per block
    const int lane = threadIdx.x & 127;               // 128 float4 per row
    const int b = row / kS;
    const int r = row - b * kS;
    const int sr = src_row(b, r, idx);
    const float4* src4 = reinterpret_cast<const float4*>(x + (size_t)sr * kD);
    float4* dst4       = reinterpret_cast<float4*>(out + (size_t)row * kD);
    dst4[lane] = src4[lane];
  } else {
    const int e = (blk - kXBlocks) * 256 + threadIdx.x;   // [0, kPosElems)
    const int row = e / 3;
    const int c   = e - row * 3;
    const int b = row / kS;
    const int r = row - b * kS;
    const int sr = src_row(b, r, idx);
    float* outp = out + (size_t)kB * kS * kD;
    outp[e] = pos[sr * 3 + c];
  }
}

extern "C" void kernel_launch(void* const* d_in, const int* in_sizes, int n_in,
                              void* d_out, int out_size, void* d_ws, size_t ws_size,
                              hipStream_t stream) {
  const float* x   = (const float*)d_in[0];   // [B*P, D] f32
  const float* pos = (const float*)d_in[1];   // [B*P, 3] f32
  // d_in[2] = batch_idx (int64): sorted equal-sized batches -> layout implied
  int* idx = (int*)d_ws;                      // [B][kN1] int32 = 64 KiB

  fps_kernel<<<kB, kTF, 0, stream>>>(pos, idx);
  gather_kernel<<<kXBlocks + kPosBlocks, 256, 0, stream>>>(x, pos, idx, (float*)d_out);
}